// Round 3
// baseline (304.245 us; speedup 1.0000x reference)
//
#include <hip/hip_runtime.h>
#include <hip/hip_bf16.h>
#include <math.h>

typedef __attribute__((ext_vector_type(8))) short short8;
typedef __attribute__((ext_vector_type(16))) float f32x16;

#define NB 4096
#define DIM 128
// EXP_SCALE = (1/TAU) * log2(e) = 20 * 1.4426950408889634
#define EXP_SCALE 28.853900817779268f

__device__ inline unsigned short f2bf(float f) {
  unsigned int u = __builtin_bit_cast(unsigned int, f);
  u += 0x7FFFu + ((u >> 16) & 1u);
  return (unsigned short)(u >> 16);
}

__device__ inline float wave_sum(float v) {
#pragma unroll
  for (int off = 32; off >= 1; off >>= 1) v += __shfl_xor(v, off, 64);
  return v;
}

// Zero rsum + detect int64-vs-int32 links (int64 hi-words of values <2^31 are
// all zero; impossible for 128 consecutive real int32 links).
__global__ __launch_bounds__(256) void k_init(float* rs, const int* links32, int* flag) {
  int i = blockIdx.x * 256 + threadIdx.x;
  if (i < 2 * NB) rs[i] = 0.0f;
  if (blockIdx.x == 0 && threadIdx.x == 0) {
    int all0 = 1;
    for (int w = 1; w < 256; w += 2) all0 &= (links32[w] == 0);
    *flag = all0;
  }
}

// Gather + L2-normalize the 8192 referenced rows.
// Outputs: f32 rows (for exact diag dot) + bf16 K-chunked layout Zc[16][4096][8]
__global__ __launch_bounds__(256) void k_normalize(
    const float* __restrict__ emb, const int* __restrict__ links,
    const int* __restrict__ flag,
    float* __restrict__ Zi_f, float* __restrict__ Zj_f,
    unsigned short* __restrict__ Zic, unsigned short* __restrict__ Zjc) {
  int wid = threadIdx.x >> 6, lane = threadIdx.x & 63;
  int r = blockIdx.x * 4 + wid;   // 0..8191
  int side = r >> 12;             // 0 => zis (links[:,0]), 1 => zjs (links[:,1])
  int p = r & (NB - 1);
  int q = 2 * p + side;
  int idx = (*flag) ? links[2 * q] : links[q];  // int64 mode: lo word
  const float* src = emb + (long long)idx * DIM;
  float x0 = src[lane], x1 = src[lane + 64];
  float ss = wave_sum(x0 * x0 + x1 * x1);
  float inv = 1.0f / fmaxf(sqrtf(ss), 1e-12f);
  x0 *= inv; x1 *= inv;
  float* Zf = side ? Zj_f : Zi_f;
  unsigned short* Zc = side ? Zjc : Zic;
  Zf[p * DIM + lane] = x0;
  Zf[p * DIM + 64 + lane] = x1;
  Zc[(((lane >> 3) + 0) * NB + p) * 8 + (lane & 7)] = f2bf(x0);
  Zc[(((lane >> 3) + 8) * NB + p) * 8 + (lane & 7)] = f2bf(x1);
}

// diag[i] = (zis_i . zjs_i) / TAU, in f32 (the softmax numerator logit)
__global__ __launch_bounds__(256) void k_diag(
    const float* __restrict__ Zi_f, const float* __restrict__ Zj_f,
    float* __restrict__ diag) {
  int wid = threadIdx.x >> 6, lane = threadIdx.x & 63;
  int i = blockIdx.x * 4 + wid;
  float a0 = Zi_f[i * DIM + lane], a1 = Zi_f[i * DIM + 64 + lane];
  float b0 = Zj_f[i * DIM + lane], b1 = Zj_f[i * DIM + 64 + lane];
  float s = wave_sum(a0 * b0 + a1 * b1);
  if (lane == 0) diag[i] = s * 20.0f;
}

// One pass: rows i of L = X.Y^T/tau, accumulate sum_j exp(L[i][j]-20),
// optionally skipping j==i. Tiles computed as T = mfma(Yfrag, Xfrag).
// FULLY layout-agnostic: two probe MFMAs measure, per (lane, reg), the
// source-lane of the arg0 operand (jmap) and arg1 operand (imap) at that
// C position — valid under ANY bijective (lane,reg)->(row,col) mapping,
// any operand-order convention, any k-slot permutation. (Round-2 bug: used
// imap[0] only, assuming col constant per lane — transposed layouts broke it.)
// z: 0=AB(X=Zi,Y=Zj,acc=a) 1=AA(skip) 2=BA(X=Zj,Y=Zi,acc=b) 3=BB(skip)
__global__ __launch_bounds__(256) void k_pass(
    const unsigned short* __restrict__ Zic, const unsigned short* __restrict__ Zjc,
    float* __restrict__ rsum_a, float* __restrict__ rsum_b) {
  int z = blockIdx.z;
  const unsigned short* Xc = (z == 0 || z == 1) ? Zic : Zjc;
  const unsigned short* Yc = (z == 1 || z == 2) ? Zic : Zjc;
  float* racc = (z < 2) ? rsum_a : rsum_b;
  const bool skip = (z & 1);

  int wid = threadIdx.x >> 6, lane = threadIdx.x & 63;
  int i0 = blockIdx.x * 256 + wid * 64;  // wave owns 64 loss-rows (2 col-tiles)
  int jb = blockIdx.y * 128;             // j-chunk of 128 (4 tiles of 32)
  int lr = lane & 31;
  int hi = lane >> 5;                    // k-half selector within fragment

  // --- dual per-reg layout probe ---
  // probe1: arg0-slots = lane-id, arg1 = 1/16  => pr[r] = arg0 source-lane
  // probe2: arg0 = 1/16, arg1-slots = lane-id  => pn[r] = arg1 source-lane
  short8 pj, pc;
  unsigned short blr = f2bf((float)lr);
#pragma unroll
  for (int e = 0; e < 8; ++e) { pj[e] = (short)blr; pc[e] = (short)0x3D80; }
  f32x16 pr = {}, pn = {};
  pr = __builtin_amdgcn_mfma_f32_32x32x16_bf16(pj, pc, pr, 0, 0, 0);
  pn = __builtin_amdgcn_mfma_f32_32x32x16_bf16(pc, pj, pn, 0, 0, 0);
  int jmap[16], imap[16];
#pragma unroll
  for (int r = 0; r < 16; ++r) {
    jmap[r] = (int)(pr[r] + 0.5f);
    imap[r] = (int)(pn[r] + 0.5f);
  }

  // Hoist X fragments for the whole j loop: 8 contiguous bf16 = 16B load
  short8 xf[2][8];
#pragma unroll
  for (int t = 0; t < 2; ++t)
#pragma unroll
    for (int ks = 0; ks < 8; ++ks)
      xf[t][ks] = *reinterpret_cast<const short8*>(
          Xc + ((size_t)(ks * 2 + hi) * NB + (i0 + t * 32 + lr)) * 8);

  float rs0[16], rs1[16];
#pragma unroll
  for (int r = 0; r < 16; ++r) { rs0[r] = 0.0f; rs1[r] = 0.0f; }

  for (int jt = 0; jt < 4; ++jt) {
    int j0 = jb + jt * 32;
    short8 yf[8];
#pragma unroll
    for (int ks = 0; ks < 8; ++ks)
      yf[ks] = *reinterpret_cast<const short8*>(
          Yc + ((size_t)(ks * 2 + hi) * NB + (j0 + lr)) * 8);
    f32x16 acc0 = {}, acc1 = {};
#pragma unroll
    for (int ks = 0; ks < 8; ++ks) {
      acc0 = __builtin_amdgcn_mfma_f32_32x32x16_bf16(yf[ks], xf[0][ks], acc0, 0, 0, 0);
      acc1 = __builtin_amdgcn_mfma_f32_32x32x16_bf16(yf[ks], xf[1][ks], acc1, 0, 0, 0);
    }
#pragma unroll
    for (int r = 0; r < 16; ++r) {
      float e0 = exp2f(fmaf(acc0[r], EXP_SCALE, -EXP_SCALE));
      float e1 = exp2f(fmaf(acc1[r], EXP_SCALE, -EXP_SCALE));
      if (skip) {
        int j = j0 + jmap[r];
        if (j == i0 + imap[r]) e0 = 0.0f;
        if (j == i0 + 32 + imap[r]) e1 = 0.0f;
      }
      rs0[r] += e0;
      rs1[r] += e1;
    }
  }
  // per-reg accumulation target (layout-agnostic)
#pragma unroll
  for (int r = 0; r < 16; ++r) {
    atomicAdd(&racc[i0 + imap[r]], rs0[r]);
    atomicAdd(&racc[i0 + 32 + imap[r]], rs1[r]);
  }
}

__global__ __launch_bounds__(256) void k_final(
    const float* __restrict__ rsum_a, const float* __restrict__ rsum_b,
    const float* __restrict__ diag, float* __restrict__ out) {
  int t = threadIdx.x;
  float local = 0.0f;
  for (int i = t; i < NB; i += 256) {
    float lse_a = 20.0f + logf(rsum_a[i]);
    float lse_b = 20.0f + logf(rsum_b[i]);
    local += 0.5f * (lse_a + lse_b) - diag[i];
  }
  local = wave_sum(local);
  __shared__ float sred[4];
  int wid = t >> 6, lane = t & 63;
  if (lane == 0) sred[wid] = local;
  __syncthreads();
  if (t == 0) out[0] = (sred[0] + sred[1] + sred[2] + sred[3]) * (1.0f / NB);
}

extern "C" void kernel_launch(void* const* d_in, const int* in_sizes, int n_in,
                              void* d_out, int out_size, void* d_ws, size_t ws_size,
                              hipStream_t stream) {
  const float* emb = (const float*)d_in[0];
  const int* links = (const int*)d_in[1];
  char* ws = (char*)d_ws;
  float* Zi_f = (float*)(ws + 0);                        // 2 MB
  float* Zj_f = (float*)(ws + 2097152);                  // 2 MB
  unsigned short* Zic = (unsigned short*)(ws + 4194304); // 1 MB
  unsigned short* Zjc = (unsigned short*)(ws + 5242880); // 1 MB
  float* rsum = (float*)(ws + 6291456);                  // 32 KB
  float* rsum_a = rsum;
  float* rsum_b = rsum + NB;
  float* diag = (float*)(ws + 6324224);                  // 16 KB
  int* flag = (int*)(ws + 6340608);
  float* out = (float*)d_out;

  hipLaunchKernelGGL(k_init, dim3(32), dim3(256), 0, stream, rsum, links, flag);
  hipLaunchKernelGGL(k_normalize, dim3(2048), dim3(256), 0, stream,
                     emb, links, flag, Zi_f, Zj_f, Zic, Zjc);
  hipLaunchKernelGGL(k_diag, dim3(1024), dim3(256), 0, stream, Zi_f, Zj_f, diag);
  hipLaunchKernelGGL(k_pass, dim3(16, 32, 4), dim3(256), 0, stream,
                     Zic, Zjc, rsum_a, rsum_b);
  hipLaunchKernelGGL(k_final, dim3(1), dim3(256), 0, stream,
                     rsum_a, rsum_b, diag, out);
}

// Round 4
// 90.332 us; speedup vs baseline: 3.3681x; 3.3681x over previous
//
#include <hip/hip_runtime.h>
#include <hip/hip_bf16.h>
#include <math.h>

typedef __attribute__((ext_vector_type(8))) short short8;
typedef __attribute__((ext_vector_type(16))) float f32x16;

#define NB 4096
#define DIM 128
#define NJ 16                  // j-splits: each block handles NB/NJ = 256 j's
#define JTILES (NB / NJ / 32)  // 8 j-tiles of 32 per block
// EXP_SCALE = (1/TAU) * log2(e) = 20 * 1.4426950408889634
#define EXP_SCALE 28.853900817779268f

__device__ inline unsigned short f2bf(float f) {
  unsigned int u = __builtin_bit_cast(unsigned int, f);
  u += 0x7FFFu + ((u >> 16) & 1u);
  return (unsigned short)(u >> 16);
}

__device__ inline float wave_sum(float v) {
#pragma unroll
  for (int off = 32; off >= 1; off >>= 1) v += __shfl_xor(v, off, 64);
  return v;
}

// Detect int64-vs-int32 links (int64 hi-words of values <2^31 are all zero;
// impossible for 128 consecutive real int32 links) + zero the output scalar.
__global__ __launch_bounds__(64) void k_init(const int* links32, int* flag, float* out) {
  if (threadIdx.x == 0) {
    int all0 = 1;
    for (int w = 1; w < 256; w += 2) all0 &= (links32[w] == 0);
    *flag = all0;
    out[0] = 0.0f;
  }
}

// Gather + L2-normalize the 8192 referenced rows.
// Outputs: f32 rows (for exact diag dot) + bf16 K-chunked layout Zc[16][4096][8]
__global__ __launch_bounds__(256) void k_normalize(
    const float* __restrict__ emb, const int* __restrict__ links,
    const int* __restrict__ flag,
    float* __restrict__ Zi_f, float* __restrict__ Zj_f,
    unsigned short* __restrict__ Zic, unsigned short* __restrict__ Zjc) {
  int wid = threadIdx.x >> 6, lane = threadIdx.x & 63;
  int r = blockIdx.x * 4 + wid;   // 0..8191
  int side = r >> 12;             // 0 => zis (links[:,0]), 1 => zjs (links[:,1])
  int p = r & (NB - 1);
  int q = 2 * p + side;
  int idx = (*flag) ? links[2 * q] : links[q];  // int64 mode: lo word
  const float* src = emb + (long long)idx * DIM;
  float x0 = src[lane], x1 = src[lane + 64];
  float ss = wave_sum(x0 * x0 + x1 * x1);
  float inv = 1.0f / fmaxf(sqrtf(ss), 1e-12f);
  x0 *= inv; x1 *= inv;
  float* Zf = side ? Zj_f : Zi_f;
  unsigned short* Zc = side ? Zjc : Zic;
  Zf[p * DIM + lane] = x0;
  Zf[p * DIM + 64 + lane] = x1;
  Zc[(((lane >> 3) + 0) * NB + p) * 8 + (lane & 7)] = f2bf(x0);
  Zc[(((lane >> 3) + 8) * NB + p) * 8 + (lane & 7)] = f2bf(x1);
}

// diag[i] = (zis_i . zjs_i) / TAU, in f32 (the softmax numerator logit)
__global__ __launch_bounds__(256) void k_diag(
    const float* __restrict__ Zi_f, const float* __restrict__ Zj_f,
    float* __restrict__ diag) {
  int wid = threadIdx.x >> 6, lane = threadIdx.x & 63;
  int i = blockIdx.x * 4 + wid;
  float a0 = Zi_f[i * DIM + lane], a1 = Zi_f[i * DIM + 64 + lane];
  float b0 = Zj_f[i * DIM + lane], b1 = Zj_f[i * DIM + 64 + lane];
  float s = wave_sum(a0 * b0 + a1 * b1);
  if (lane == 0) diag[i] = s * 20.0f;
}

// One pass: rows i of L = X.Y^T/tau, accumulate sum_j exp(L[i][j]-20),
// optionally skipping j==i. Layout-agnostic via dual per-reg probe MFMAs
// (measure source-row lr of arg0 (jmap) and arg1 (imap) per (lane,reg)).
// No global atomics: per-reg register partials across the whole j-loop ->
// one LDS reduce -> plain store into a private slice rpart[z][by][i].
// z: 0=AB(X=Zi,Y=Zj) 1=AA(skip) 2=BA(X=Zj,Y=Zi) 3=BB(skip); a = z<2, b = z>=2
__global__ __launch_bounds__(256) void k_pass(
    const unsigned short* __restrict__ Zic, const unsigned short* __restrict__ Zjc,
    float* __restrict__ rpart) {
  int z = blockIdx.z;
  const unsigned short* Xc = (z <= 1) ? Zic : Zjc;
  const unsigned short* Yc = (z == 1 || z == 2) ? Zic : Zjc;
  const bool skip = (z & 1);

  __shared__ float buf[256];
  int tid = threadIdx.x;
  int wid = tid >> 6, lane = tid & 63;
  buf[tid] = 0.0f;
  __syncthreads();

  int i0 = blockIdx.x * 256 + wid * 64;  // wave owns 64 loss-rows (2 col-tiles)
  int jb = blockIdx.y * (NB / NJ);       // 256 j's = 8 tiles of 32
  int lr = lane & 31;
  int hi = lane >> 5;                    // k-half selector within fragment

  // --- dual per-reg layout probe (verified in R3) ---
  short8 pj, pc;
  unsigned short blr = f2bf((float)lr);
#pragma unroll
  for (int e = 0; e < 8; ++e) { pj[e] = (short)blr; pc[e] = (short)0x3D80; }
  f32x16 pr = {}, pn = {};
  pr = __builtin_amdgcn_mfma_f32_32x32x16_bf16(pj, pc, pr, 0, 0, 0);
  pn = __builtin_amdgcn_mfma_f32_32x32x16_bf16(pc, pj, pn, 0, 0, 0);
  int jmap[16], imap[16];
#pragma unroll
  for (int r = 0; r < 16; ++r) {
    jmap[r] = (int)(pr[r] + 0.5f);
    imap[r] = (int)(pn[r] + 0.5f);
  }

  // Hoist X fragments for the whole j loop: 8 contiguous bf16 = 16B load
  short8 xf[2][8];
#pragma unroll
  for (int t = 0; t < 2; ++t)
#pragma unroll
    for (int ks = 0; ks < 8; ++ks)
      xf[t][ks] = *reinterpret_cast<const short8*>(
          Xc + ((size_t)(ks * 2 + hi) * NB + (i0 + t * 32 + lr)) * 8);

  float rs0[16], rs1[16];
#pragma unroll
  for (int r = 0; r < 16; ++r) { rs0[r] = 0.0f; rs1[r] = 0.0f; }

  for (int jt = 0; jt < JTILES; ++jt) {
    int j0 = jb + jt * 32;
    short8 yf[8];
#pragma unroll
    for (int ks = 0; ks < 8; ++ks)
      yf[ks] = *reinterpret_cast<const short8*>(
          Yc + ((size_t)(ks * 2 + hi) * NB + (j0 + lr)) * 8);
    f32x16 acc0 = {}, acc1 = {};
#pragma unroll
    for (int ks = 0; ks < 8; ++ks) {
      acc0 = __builtin_amdgcn_mfma_f32_32x32x16_bf16(yf[ks], xf[0][ks], acc0, 0, 0, 0);
      acc1 = __builtin_amdgcn_mfma_f32_32x32x16_bf16(yf[ks], xf[1][ks], acc1, 0, 0, 0);
    }
    // diag can only hit a tile whose j-range intersects the wave's i-range
    int d0 = j0 - i0, d1 = j0 - (i0 + 32);
    bool chk0 = skip && ((unsigned)(d0 + 31) <= 62u);
    bool chk1 = skip && ((unsigned)(d1 + 31) <= 62u);
#pragma unroll
    for (int r = 0; r < 16; ++r) {
      float e0 = exp2f(fmaf(acc0[r], EXP_SCALE, -EXP_SCALE));
      float e1 = exp2f(fmaf(acc1[r], EXP_SCALE, -EXP_SCALE));
      if (chk0 && (jmap[r] + d0 == imap[r])) e0 = 0.0f;
      if (chk1 && (jmap[r] + d1 == imap[r])) e1 = 0.0f;
      rs0[r] += e0;
      rs1[r] += e1;
    }
  }
  // LDS reduce (2 lanes x 16 regs share each output column)
  int base = wid * 64;
#pragma unroll
  for (int r = 0; r < 16; ++r) {
    atomicAdd(&buf[base + imap[r]], rs0[r]);
    atomicAdd(&buf[base + 32 + imap[r]], rs1[r]);
  }
  __syncthreads();
  rpart[((size_t)(z * NJ + blockIdx.y)) * NB + blockIdx.x * 256 + tid] = buf[tid];
}

__global__ __launch_bounds__(256) void k_final(
    const float* __restrict__ rpart, const float* __restrict__ diag,
    float* __restrict__ out) {
  int i = blockIdx.x * 256 + threadIdx.x;
  float sa = 0.0f, sb = 0.0f;
#pragma unroll
  for (int y = 0; y < NJ; ++y) {
    sa += rpart[(size_t)(0 * NJ + y) * NB + i] + rpart[(size_t)(1 * NJ + y) * NB + i];
    sb += rpart[(size_t)(2 * NJ + y) * NB + i] + rpart[(size_t)(3 * NJ + y) * NB + i];
  }
  // 0.5*(lse_a + lse_b) - diag ; lse = 20 + ln(sum)
  float v = 0.5f * (40.0f + logf(sa) + logf(sb)) - diag[i];
  v = wave_sum(v);
  __shared__ float sred[4];
  if ((threadIdx.x & 63) == 0) sred[threadIdx.x >> 6] = v;
  __syncthreads();
  if (threadIdx.x == 0)
    atomicAdd(out, (sred[0] + sred[1] + sred[2] + sred[3]) * (1.0f / NB));
}

extern "C" void kernel_launch(void* const* d_in, const int* in_sizes, int n_in,
                              void* d_out, int out_size, void* d_ws, size_t ws_size,
                              hipStream_t stream) {
  const float* emb = (const float*)d_in[0];
  const int* links = (const int*)d_in[1];
  char* ws = (char*)d_ws;
  float* Zi_f = (float*)(ws + 0);                        // 2 MB
  float* Zj_f = (float*)(ws + 2097152);                  // 2 MB
  unsigned short* Zic = (unsigned short*)(ws + 4194304); // 1 MB
  unsigned short* Zjc = (unsigned short*)(ws + 5242880); // 1 MB
  float* rpart = (float*)(ws + 6291456);                 // 4*NJ*NB*4 = 1 MB
  float* diag = (float*)(ws + 7340032);                  // 16 KB
  int* flag = (int*)(ws + 7356416);                      // 4 B
  float* out = (float*)d_out;

  hipLaunchKernelGGL(k_init, dim3(1), dim3(64), 0, stream, links, flag, out);
  hipLaunchKernelGGL(k_normalize, dim3(2048), dim3(256), 0, stream,
                     emb, links, flag, Zi_f, Zj_f, Zic, Zjc);
  hipLaunchKernelGGL(k_diag, dim3(1024), dim3(256), 0, stream, Zi_f, Zj_f, diag);
  hipLaunchKernelGGL(k_pass, dim3(16, NJ, 4), dim3(256), 0, stream,
                     Zic, Zjc, rpart);
  hipLaunchKernelGGL(k_final, dim3(16), dim3(256), 0, stream,
                     rpart, diag, out);
}